// Round 4
// baseline (846.138 us; speedup 1.0000x reference)
//
#include <hip/hip_runtime.h>
#include <hip/hip_bf16.h>
#include <math.h>

// ---------------------------------------------------------------------------
// ContextualAttention: y[b,p,q] = softmax_p( 10 * mm[p] * T[p][q] / denom[b,p] ) * mm[p]
//   S[b][u][v] = Σ_c b_in[b,c,u] * f_in[b,c,v]   (K=128 GEMM, bf16x2-split MFMA)
//   T[p][q] = Σ_s S[p+s][q+s], s = 64dy+dx (9 diagonal taps, masked at edges)
//
// Diagonal restructure: S is stored diagonal-major SD[t][e] = S[t][(t-e)&4095].
// All 9 taps of T[p][q] lie on diagonal d=(p-q)&4095: tap = SD[t+s][d].
// k_pass walks t with d fixed per thread: 3 new aligned scalar loads/output
// (6 taps carried in registers), computes e = exp2(coef[t]*T), writes e*mm
// straight to out, and accumulates column sums (softmax denominator) in a
// wave-private sliding LDS window (ds_add_f32) flushed by global atomics.
// k_scale then streams out *= linv[q]. The old 9-tap two-pass stencil
// (k_sumexp + k_write, ~420 us combined) is gone.
// ---------------------------------------------------------------------------

typedef float f32x4 __attribute__((ext_vector_type(4)));
typedef short bf16x8 __attribute__((ext_vector_type(8)));

#define NB 4
#define NC 128
#define NP 4096ull       // 64*64 spatial positions
#define LOG2E_SCALE 14.426950408889634f   // 10 * log2(e)
#define EPS_TERM (1152.0f * 1e-4f)
#define TCH 256          // t-chunk per k_pass block

// ---- workspace layout (bytes) ----
#define SZ_S      (4ull * NP * NP * 4ull)            // 268435456 (SD, diagonal-major)
#define SZ_BT     (4ull * NP * NC * 2ull)            // 4194304 (bf16 [b][u][c])
#define OFF_S     1024ull
#define OFF_BT_HI (OFF_S + SZ_S + 1024ull)
#define OFF_BT_LO (OFF_BT_HI + SZ_BT)
#define OFF_FT_HI (OFF_BT_LO + SZ_BT)
#define OFF_FT_LO (OFF_FT_HI + SZ_BT)
#define OFF_NORM2 (OFF_FT_LO + SZ_BT)
#define OFF_COEF  (OFF_NORM2 + 4ull * NP * 4ull)     // 4*4096 f32
#define OFF_MM    (OFF_COEF + 4ull * NP * 4ull)      // 4096 f32
#define OFF_GSUM  (OFF_MM + NP * 4ull)               // 4*4096 f32 (softmax denom)
#define OFF_LINV  (OFF_GSUM + 4ull * NP * 4ull)      // 4*4096 f32

// ---------------------------------------------------------------------------
// norm2[b][u] = sum_c b_in[b,c,u]^2
__global__ __launch_bounds__(256) void k_norm2(const float* __restrict__ bin,
                                               float* __restrict__ norm2) {
    int idx = blockIdx.x * 256 + threadIdx.x;       // 16384 = 4*4096
    int b = idx >> 12, u = idx & 4095;
    const float* src = bin + (size_t)b * NC * NP + u;
    float s = 0.f;
#pragma unroll 8
    for (int c = 0; c < NC; ++c) { float x = src[(size_t)c * NP]; s += x * x; }
    norm2[idx] = s;
}

// coef[b][p] = mm[p] * 10*log2(e) / sqrt(boxsum3x3(norm2) + 1152*EPS)
// Also zeroes gsum (softmax denominator accumulator, same 4*4096 shape).
__global__ __launch_bounds__(256) void k_coef(const float* __restrict__ norm2,
                                              const float* __restrict__ mask,
                                              float* __restrict__ coef,
                                              float* __restrict__ mmArr,
                                              float* __restrict__ gsum) {
    int idx = blockIdx.x * 256 + threadIdx.x;       // 16384
    int b = idx >> 12, p = idx & 4095;
    int ph = p >> 6, pw = p & 63;
    float ns = 0.f, ms = 0.f;
#pragma unroll
    for (int dy = -1; dy <= 1; ++dy)
#pragma unroll
        for (int dx = -1; dx <= 1; ++dx) {
            int hh = ph + dy, ww = pw + dx;
            if ((unsigned)hh < 64u && (unsigned)ww < 64u) {
                ns += norm2[b * 4096 + hh * 64 + ww];
                ms += mask[(size_t)(hh * 512 + ww) * 8];
            }
        }
    float mmv = (ms == 0.f) ? 1.f : 0.f;
    coef[idx] = mmv * LOG2E_SCALE / sqrtf(ns + EPS_TERM);
    if (b == 0) mmArr[p] = mmv;
    gsum[idx] = 0.f;
}

// ---------------------------------------------------------------------------
// Transpose [c][u] f32 -> [u][c] bf16 hi/lo split (per batch, per input array)
__global__ __launch_bounds__(256) void k_convert(const float* __restrict__ fin,
                                                 const float* __restrict__ bin,
                                                 __bf16* __restrict__ bt_hi, __bf16* __restrict__ bt_lo,
                                                 __bf16* __restrict__ ft_hi, __bf16* __restrict__ ft_lo) {
    __shared__ float tile[64][65];
    int u0 = blockIdx.x * 64;
    int k0 = blockIdx.y * 64;
    int z = blockIdx.z;                  // 0..7 : (batch<<1)|arr
    int arr = z & 1, b = z >> 1;
    const float* src = (arr ? fin : bin) + (size_t)b * NC * NP;
    __bf16* dhi = (arr ? ft_hi : bt_hi) + (size_t)b * NP * NC;
    __bf16* dlo = (arr ? ft_lo : bt_lo) + (size_t)b * NP * NC;
    int t = threadIdx.x;
#pragma unroll
    for (int i = 0; i < 16; ++i) {
        int lin = i * 256 + t;
        int kl = lin >> 6, ul = lin & 63;
        tile[kl][ul] = src[(size_t)(k0 + kl) * NP + u0 + ul];
    }
    __syncthreads();
#pragma unroll
    for (int i = 0; i < 16; ++i) {
        int lin = i * 256 + t;
        int ul = lin >> 6, kl = lin & 63;   // consecutive t -> consecutive kl (coalesced out)
        float x = tile[kl][ul];
        __bf16 h = (__bf16)x;
        float hf = (float)h;
        __bf16 l = (__bf16)(x - hf);
        size_t o = (size_t)(u0 + ul) * NC + (k0 + kl);
        dhi[o] = h; dlo[o] = l;
    }
}

// ---------------------------------------------------------------------------
// SD[b][row][(row-col)&4095] = sum_c bT[row][c] * fT[col][c]
// 16x16x32 bf16 MFMA, 3-term hi/lo split. Block: 256 thr = 4 waves (2x2),
// tile 128x128; each wave 64x64 (4x4 MFMA tiles). Epilogue writes the
// DIAGONAL-MAJOR layout; per store instr lanes l15 give 16 consecutive
// (descending) e values -> same 64B-segment coalescing as row-major.
__global__ __launch_bounds__(256) void k_matmul(const __bf16* __restrict__ bt_hi,
                                                const __bf16* __restrict__ bt_lo,
                                                const __bf16* __restrict__ ft_hi,
                                                const __bf16* __restrict__ ft_lo,
                                                float* __restrict__ S) {
    int t = threadIdx.x;
    int lane = t & 63;
    int w = t >> 6;
    int b = blockIdx.z;
    int m_base = blockIdx.y * 128 + (w >> 1) * 64;
    int n_base = blockIdx.x * 128 + (w & 1) * 64;
    int l15 = lane & 15;
    int quad = lane >> 4;
    size_t bo = (size_t)b * NP * NC;
    const __bf16* Ah = bt_hi + bo;
    const __bf16* Al = bt_lo + bo;
    const __bf16* Bh = ft_hi + bo;
    const __bf16* Bl = ft_lo + bo;

    f32x4 acc[4][4];
#pragma unroll
    for (int i = 0; i < 4; ++i)
#pragma unroll
        for (int j = 0; j < 4; ++j) acc[i][j] = (f32x4){0.f, 0.f, 0.f, 0.f};

#pragma unroll
    for (int ks = 0; ks < 4; ++ks) {
        int k = ks * 32 + quad * 8;      // A[m=l15][k..k+7], contiguous in memory
        bf16x8 ah[4], al[4], bh[4], bl[4];
#pragma unroll
        for (int mt = 0; mt < 4; ++mt) {
            size_t o = (size_t)(m_base + mt * 16 + l15) * NC + k;
            ah[mt] = *(const bf16x8*)(Ah + o);
            al[mt] = *(const bf16x8*)(Al + o);
        }
#pragma unroll
        for (int nt = 0; nt < 4; ++nt) {
            size_t o = (size_t)(n_base + nt * 16 + l15) * NC + k;
            bh[nt] = *(const bf16x8*)(Bh + o);
            bl[nt] = *(const bf16x8*)(Bl + o);
        }
#pragma unroll
        for (int mt = 0; mt < 4; ++mt)
#pragma unroll
            for (int nt = 0; nt < 4; ++nt) {
                acc[mt][nt] = __builtin_amdgcn_mfma_f32_16x16x32_bf16(ah[mt], bh[nt], acc[mt][nt], 0, 0, 0);
                acc[mt][nt] = __builtin_amdgcn_mfma_f32_16x16x32_bf16(ah[mt], bl[nt], acc[mt][nt], 0, 0, 0);
                acc[mt][nt] = __builtin_amdgcn_mfma_f32_16x16x32_bf16(al[mt], bh[nt], acc[mt][nt], 0, 0, 0);
            }
    }
    // C/D layout (m89-verified): col = lane&15, row = quad*4 + reg
    float* Sb = S + (size_t)b * NP * NP;
#pragma unroll
    for (int mt = 0; mt < 4; ++mt)
#pragma unroll
        for (int nt = 0; nt < 4; ++nt) {
            int col = n_base + nt * 16 + l15;
            int row0 = m_base + mt * 16 + quad * 4;
#pragma unroll
            for (int r = 0; r < 4; ++r) {
                int row = row0 + r;
                Sb[(size_t)row * NP + ((row - col) & 4095)] = acc[mt][nt][r];
            }
        }
}

// ---------------------------------------------------------------------------
// Fused stencil+exp+write pass along diagonals.
// Thread owns diagonal d, walks t in [t0, t0+TCH). Taps: SD[t+s][d],
// s in {-65..-63,-1..1,63..65}: 3 bands x 3 taps; 2 taps/band carried in
// registers, 1 new aligned scalar load/band/step (wave reads 256B/load).
// Masks factor: okw(dx) from (pw,qw) edges, okh(dy) from (ph,qh) edges.
// e = exp2(coef[t]*T) accumulated into wave-private sliding LDS window
// (ds_add_f32: commutative, no ordering hazard, conflict-free stride-1);
// e*mm[t] stored straight to out (lanes -> consecutive descending q).
__global__ __launch_bounds__(256) void k_pass(const float* __restrict__ SD,
                                              const float* __restrict__ coef,
                                              const float* __restrict__ mmArr,
                                              float* __restrict__ out,
                                              float* __restrict__ gsum) {
    // XCD-chunked bijective swizzle (1024 blocks % 8 == 0): consecutive
    // t-chunks (overlapping halos) land on the same XCD's L2.
    int orig = blockIdx.x;
    int wg = (orig & 7) * 128 + (orig >> 3);
    int tc = wg & 15;               // t-chunk   0..15
    int dc = (wg >> 4) & 15;        // d-chunk   0..15
    int b  = wg >> 8;               // batch     0..3
    int t0 = tc * TCH;
    int d  = dc * 256 + threadIdx.x;
    int lane = threadIdx.x & 63;
    int w = threadIdx.x >> 6;
    const float* SDb = SD + (size_t)b * NP * NP;
    const float* cf  = coef + (b << 12);
    float* outb = out + (size_t)b * NP * NP;

    __shared__ float win[4][TCH + 64];          // wave-private: no barriers
    for (int s = lane; s < TCH + 64; s += 64) win[w][s] = 0.f;

    // D(i) = SD[clamp(i,0,4095)][d] (out-of-range rows are always masked)
#define DLOAD(i) (SDb[(size_t)((i) < 0 ? 0 : ((i) > 4095 ? 4095 : (i))) * NP + d])
    float am1 = DLOAD(t0 - 65), a0 = DLOAD(t0 - 64), ap1 = DLOAD(t0 - 63);
    float bm1 = DLOAD(t0 - 1),  b0 = DLOAD(t0),      bp1 = DLOAD(t0 + 1);
    float cm1 = DLOAD(t0 + 63), c0 = DLOAD(t0 + 64), cp1 = DLOAD(t0 + 65);

#pragma unroll 4
    for (int ti = 0; ti < TCH; ++ti) {
        int t = t0 + ti;
        // prefetch next step's taps (1-deep; independent of this step's compute)
        float ap2 = DLOAD(t - 62);
        float bp2 = DLOAD(t + 2);
        float cp2 = DLOAD(t + 66);
        int q  = (t - d) & 4095;
        int qw = q & 63, qh = q >> 6;
        int pw = t & 63, ph = t >> 6;          // wave-uniform
        bool lv = (pw > 0)  & (qw > 0);        // dx = -1 valid
        bool rv = (pw < 63) & (qw < 63);       // dx = +1 valid
        bool uv = (ph > 0)  & (qh > 0);        // dy = -1 valid
        bool dv = (ph < 63) & (qh < 63);       // dy = +1 valid
        float Vm = a0 + (lv ? am1 : 0.f) + (rv ? ap1 : 0.f);
        float V0 = b0 + (lv ? bm1 : 0.f) + (rv ? bp1 : 0.f);
        float Vp = c0 + (lv ? cm1 : 0.f) + (rv ? cp1 : 0.f);
        float T  = V0 + (uv ? Vm : 0.f) + (dv ? Vp : 0.f);
        float e  = exp2f(cf[t] * T);           // masked rows: coef=0 -> e=1
        atomicAdd(&win[w][ti + 63 - lane], e); // ds_add_f32, stride-1, no conflicts
        outb[(size_t)t * NP + q] = e * mmArr[t];
        am1 = a0; a0 = ap1; ap1 = ap2;
        bm1 = b0; b0 = bp1; bp1 = bp2;
        cm1 = c0; c0 = cp1; cp1 = cp2;
    }
#undef DLOAD
    // flush wave window to global denominator (same wave: ordered, no barrier)
    float* gs = gsum + (b << 12);
    int dw = dc * 256 + w * 64;
    int qb = t0 - dw - 63;
    for (int s = lane; s < TCH + 63; s += 64)
        atomicAdd(&gs[(qb + s) & 4095], win[w][s]);
}

// linv[b][q] = 1 / gsum[b][q]
__global__ __launch_bounds__(256) void k_linv(const float* __restrict__ gsum,
                                              float* __restrict__ linv) {
    int idx = blockIdx.x * 256 + threadIdx.x;  // 16384
    linv[idx] = 1.0f / gsum[idx];
}

// out[b][p][q] *= linv[b][q]   (pure streaming scale, f32x4)
__global__ __launch_bounds__(256) void k_scale(float* __restrict__ out,
                                               const float* __restrict__ linv) {
    const size_t NV = 4ull * NP * NP / 4ull;   // 16777216 vecs; 32 iters/thread
    for (size_t v = (size_t)blockIdx.x * 256 + threadIdx.x; v < NV; v += 2048ull * 256ull) {
        size_t e0 = v << 2;
        int q = (int)(e0 & 4095);
        int b = (int)(e0 >> 24);
        f32x4 x = *(f32x4*)(out + e0);
        f32x4 L = *(const f32x4*)(linv + ((size_t)b << 12) + q);
        x.x *= L.x; x.y *= L.y; x.z *= L.z; x.w *= L.w;
        *(f32x4*)(out + e0) = x;
    }
}

// ---------------------------------------------------------------------------
extern "C" void kernel_launch(void* const* d_in, const int* in_sizes, int n_in,
                              void* d_out, int out_size, void* d_ws, size_t ws_size,
                              hipStream_t stream) {
    (void)in_sizes; (void)n_in; (void)out_size; (void)ws_size;
    const float* f_in = (const float*)d_in[0];
    const float* b_in = (const float*)d_in[1];
    const float* mask = (const float*)d_in[2];
    float* out = (float*)d_out;
    char* ws = (char*)d_ws;

    float*  S     = (float*)(ws + OFF_S);
    __bf16* bt_hi = (__bf16*)(ws + OFF_BT_HI);
    __bf16* bt_lo = (__bf16*)(ws + OFF_BT_LO);
    __bf16* ft_hi = (__bf16*)(ws + OFF_FT_HI);
    __bf16* ft_lo = (__bf16*)(ws + OFF_FT_LO);
    float*  norm2 = (float*)(ws + OFF_NORM2);
    float*  coef  = (float*)(ws + OFF_COEF);
    float*  mmArr = (float*)(ws + OFF_MM);
    float*  gsum  = (float*)(ws + OFF_GSUM);
    float*  linv  = (float*)(ws + OFF_LINV);

    k_norm2  <<<64, 256, 0, stream>>>(b_in, norm2);
    k_coef   <<<64, 256, 0, stream>>>(norm2, mask, coef, mmArr, gsum);
    k_convert<<<dim3(64, 2, 8), 256, 0, stream>>>(f_in, b_in, bt_hi, bt_lo, ft_hi, ft_lo);
    k_matmul <<<dim3(32, 32, 4), 256, 0, stream>>>(bt_hi, bt_lo, ft_hi, ft_lo, S);
    k_pass   <<<1024, 256, 0, stream>>>(S, coef, mmArr, out, gsum);
    k_linv   <<<64, 256, 0, stream>>>(gsum, linv);
    k_scale  <<<2048, 256, 0, stream>>>(out, linv);
}